// Round 2
// baseline (57101.068 us; speedup 1.0000x reference)
//
#include <hip/hip_runtime.h>

#define HH 100
#define G4 400
#define LL 4096
#define NT 1024
#define NREG_GATES 224           // Whh1 rows held in thread registers (tids 800..1023)
#define NLDS_GATES 176           // Whh1 rows streamed from LDS (gates 224..399)
#define NQ (4*NLDS_GATES)        // 704 quarter-dot threads

// LDS floats: x[4096] h1[100] h2[100] part[1024] q[704] wq[4*176*25]
#define LDS_FLOATS (4096 + 100 + 100 + 1024 + NQ + 4*NLDS_GATES*25)

__device__ __forceinline__ float sigmoidf_(float x) {
    return 1.0f / (1.0f + __expf(-x));
}
__device__ __forceinline__ float tanhf_(float x) {
    return 1.0f - 2.0f / (__expf(2.0f * x) + 1.0f);
}

__global__ __launch_bounds__(NT, 4)
void lstm_pipe_kernel(const float* __restrict__ x_seq,
                      const float* __restrict__ Wih0,
                      const float* __restrict__ Whh0,
                      const float* __restrict__ bih0,
                      const float* __restrict__ bhh0,
                      const float* __restrict__ Wih1,
                      const float* __restrict__ Whh1,
                      const float* __restrict__ bih1,
                      const float* __restrict__ bhh1,
                      const float* __restrict__ Wlin,
                      const float* __restrict__ blin,
                      float* __restrict__ out)
{
    extern __shared__ float lds[];
    float* x_s    = lds;                  // [4096]
    float* h1_s   = x_s + LL;             // [100]
    float* h2_s   = h1_s + HH;            // [100]
    float* part_s = h2_s + HH;            // [1024]: [0,400) L0 dots, [400,800) L1-in, [800,1024) L1-rec(reg gates)
    float* q_s    = part_s + NT;          // [704] quarter partials for gates 224..399
    float* wq_s   = q_s + NQ;             // [4][176][25] quarter-major Whh1 rows 224..399

    const int tid = threadIdx.x;

    // ---- prologue: stage x and LDS weights ----
    {
        const float4* src = reinterpret_cast<const float4*>(x_seq);
        float4*       dst = reinterpret_cast<float4*>(x_s);
        for (int i = tid; i < LL/4; i += NT) dst[i] = src[i];
    }
    for (int idx = tid; idx < 4*NLDS_GATES*25; idx += NT) {
        int r   = idx / (NLDS_GATES*25);
        int rem = idx % (NLDS_GATES*25);
        int g   = rem / 25;
        int j   = rem % 25;
        wq_s[idx] = Whh1[(NREG_GATES + g)*HH + r*25 + j];
    }
    if (tid < HH) { h1_s[tid] = 0.0f; h2_s[tid] = 0.0f; }

    // ---- per-thread register weights (<=100 floats each) ----
    float4 w[25];
    float bias = 0.0f, wx = 0.0f;
    {
        const float* wrow;
        if (tid < G4) {
            wrow = Whh0 + tid*HH;
            bias = bih0[tid] + bhh0[tid];
            wx   = Wih0[tid];
        } else if (tid < 800) {
            int g = tid - G4;
            wrow = Wih1 + g*HH;
            bias = bih1[g] + bhh1[g];
        } else {
            int g = tid - 800;            // < 224
            wrow = Whh1 + g*HH;
        }
        const float4* w4 = reinterpret_cast<const float4*>(wrow);
        #pragma unroll
        for (int j = 0; j < 25; ++j) w[j] = w4[j];
    }
    const float wl = (tid < HH) ? Wlin[tid] : 0.0f;

    float c0 = 0.0f, c1 = 0.0f;
    __syncthreads();

    // ---- pipelined recurrence: iter t computes L0 step t and L1 step t-1 ----
    for (int t = 0; t <= LL; ++t) {
        // === compute phase: all dots (uniform main dot across all 1024 threads) ===
        {
            const float4* h4 = reinterpret_cast<const float4*>(tid < 800 ? h1_s : h2_s);
            float a0 = 0.f, a1 = 0.f, a2 = 0.f, a3 = 0.f;
            #pragma unroll
            for (int j = 0; j < 25; ++j) {
                float4 h = h4[j];
                a0 = fmaf(w[j].x, h.x, a0);
                a1 = fmaf(w[j].y, h.y, a1);
                a2 = fmaf(w[j].z, h.z, a2);
                a3 = fmaf(w[j].w, h.w, a3);
            }
            const int tc = (t < LL) ? t : (LL-1);
            part_s[tid] = (a0 + a1) + (a2 + a3) + bias + wx * x_s[tc];
        }
        // quarter duty: gates 224..399 of Whh1 . h2, 25 MACs each
        if (tid < NQ) {
            const int qg = tid >> 2, qr = tid & 3;
            const float* wp = wq_s + (qr*NLDS_GATES + qg)*25;
            const float* hp = h2_s + qr*25;
            float b0 = 0.f, b1 = 0.f;
            #pragma unroll
            for (int j = 0; j < 24; j += 2) {
                b0 = fmaf(wp[j],   hp[j],   b0);
                b1 = fmaf(wp[j+1], hp[j+1], b1);
            }
            q_s[tid] = fmaf(wp[24], hp[24], b0 + b1);
        }
        __syncthreads();

        // === gating phase ===
        if (tid < HH) {                       // layer-0 gating -> h1(t)
            if (t < LL) {
                float gi = part_s[tid];
                float gf = part_s[tid + 100];
                float gg = part_s[tid + 200];
                float go = part_s[tid + 300];
                c0 = sigmoidf_(gf)*c0 + sigmoidf_(gi)*tanhf_(gg);
                h1_s[tid] = sigmoidf_(go)*tanhf_(c0);
            }
        } else if (tid >= 128 && tid < 128 + HH) {   // layer-1 gating -> h2(t-1)
            if (t >= 1) {
                const int j = tid - 128;
                float v[4];
                #pragma unroll
                for (int k = 0; k < 4; ++k) {
                    int gg = j + k*100;
                    float r;
                    if (gg < NREG_GATES) {
                        r = part_s[800 + gg];
                    } else {
                        int b = 4*(gg - NREG_GATES);
                        r = (q_s[b] + q_s[b+1]) + (q_s[b+2] + q_s[b+3]);
                    }
                    v[k] = part_s[400 + gg] + r;
                }
                c1 = sigmoidf_(v[1])*c1 + sigmoidf_(v[0])*tanhf_(v[2]);
                h2_s[j] = sigmoidf_(v[3])*tanhf_(c1);
            }
        }
        __syncthreads();
    }

    // ---- final projection: out = h2(L-1) . Wlin + blin ----
    if (tid < HH) part_s[tid] = wl * h2_s[tid];
    __syncthreads();
    if (tid == 0) {
        float s = 0.0f;
        for (int k = 0; k < HH; ++k) s += part_s[k];
        out[0] = s + blin[0];
    }
}

extern "C" void kernel_launch(void* const* d_in, const int* in_sizes, int n_in,
                              void* d_out, int out_size, void* d_ws, size_t ws_size,
                              hipStream_t stream) {
    (void)in_sizes; (void)n_in; (void)out_size; (void)d_ws; (void)ws_size;

    const float* x_seq = (const float*)d_in[0];
    const float* Wih0  = (const float*)d_in[1];
    const float* Whh0  = (const float*)d_in[2];
    const float* bih0  = (const float*)d_in[3];
    const float* bhh0  = (const float*)d_in[4];
    const float* Wih1  = (const float*)d_in[5];
    const float* Whh1  = (const float*)d_in[6];
    const float* bih1  = (const float*)d_in[7];
    const float* bhh1  = (const float*)d_in[8];
    const float* Wlin  = (const float*)d_in[9];
    const float* blin  = (const float*)d_in[10];
    float* out = (float*)d_out;

    static bool attr_set = false;
    if (!attr_set) {
        hipFuncSetAttribute((const void*)lstm_pipe_kernel,
                            hipFuncAttributeMaxDynamicSharedMemorySize,
                            LDS_FLOATS * (int)sizeof(float));
        attr_set = true;
    }

    hipLaunchKernelGGL(lstm_pipe_kernel, dim3(1), dim3(NT),
                       LDS_FLOATS * sizeof(float), stream,
                       x_seq, Wih0, Whh0, bih0, bhh0,
                       Wih1, Whh1, bih1, bhh1, Wlin, blin, out);
}

// Round 3
// 8714.606 us; speedup vs baseline: 6.5523x; 6.5523x over previous
//
#include <hip/hip_runtime.h>

#define HH   100
#define LL   4096
#define NT   512
#define NLDSROW 176          // W_all rows 0..175 (= Whh0 gates 0..175) streamed from LDS
#define RB0  176             // first register-resident row
// W_all rows: [0,400) Whh0 (h1), [400,800) Wih1 (h1), [800,1200) Whh1 (h2)
// Each thread: 4 rows x one k-half (50 cols padded to 52) in registers = 208 floats.

// LDS floats: x[4096] wq[100*176] h1[104] h2[104] part[2048] q[352]
#define LDS_FLOATS (4096 + 100*176 + 104 + 104 + 2048 + 352)

__device__ __forceinline__ float sigmoidf_(float x) {
    return 1.0f / (1.0f + __expf(-x));
}
__device__ __forceinline__ float tanhf_(float x) {
    return 1.0f - 2.0f / (__expf(2.0f * x) + 1.0f);
}

__global__ __launch_bounds__(NT, 1)
void lstm_half_kernel(const float* __restrict__ x_seq,
                      const float* __restrict__ Wih0,
                      const float* __restrict__ Whh0,
                      const float* __restrict__ bih0,
                      const float* __restrict__ bhh0,
                      const float* __restrict__ Wih1,
                      const float* __restrict__ Whh1,
                      const float* __restrict__ bih1,
                      const float* __restrict__ bhh1,
                      const float* __restrict__ Wlin,
                      const float* __restrict__ blin,
                      float* __restrict__ out)
{
    extern __shared__ float lds[];
    float* x_s    = lds;                    // [4096]
    float* wq_s   = x_s + LL;               // [100*176], layout [j][r]: wq_s[j*176+r]
    float* h1_s   = wq_s + 100*NLDSROW;     // [104] padded: h[e] at e + 2*(e>=50)
    float* h2_s   = h1_s + 104;             // [104]
    float* part_s = h2_s + 104;             // [2048]: slot = ((row-176)>>2) + ((row-176)&3)*256 + half*1024
    float* q_s    = part_s + 2048;          // [352]: row + 176*half

    const int tid  = threadIdx.x;
    const int half = tid & 1;
    const int qid  = tid >> 1;              // 0..255
    const int rowbase = RB0 + 4*qid;        // 176..1196, region-aligned (400/800 are multiples of 4)

    // ---- prologue: x (coalesced) ----
    {
        const float4* src = reinterpret_cast<const float4*>(x_seq);
        float4*       dst = reinterpret_cast<float4*>(x_s);
        for (int i = tid; i < LL/4; i += NT) dst[i] = src[i];
    }
    // ---- wq: transposed Whh0 rows 0..175 (coalesced global read, scattered LDS write) ----
    for (int idx = tid; idx < NLDSROW*HH; idx += NT) {
        int r = idx / HH, j = idx % HH;
        wq_s[j*NLDSROW + r] = Whh0[idx];
    }
    if (tid < 104) { h1_s[tid] = 0.0f; h2_s[tid] = 0.0f; }

    // ---- per-thread register weights: 4 rows x 52 (padded) ----
    const float* M; int r0;
    if (rowbase < 400)      { M = Whh0; r0 = rowbase; }
    else if (rowbase < 800) { M = Wih1; r0 = rowbase - 400; }
    else                    { M = Whh1; r0 = rowbase - 800; }

    float4 w[4][13];
    #pragma unroll
    for (int i = 0; i < 4; ++i) {
        const float2* s2 = reinterpret_cast<const float2*>(M + (r0 + i)*HH + half*50);
        #pragma unroll
        for (int jj = 0; jj < 25; ++jj) {
            float2 v = s2[jj];
            if (jj & 1) { w[i][jj>>1].z = v.x; w[i][jj>>1].w = v.y; }
            else        { w[i][jj>>1].x = v.x; w[i][jj>>1].y = v.y; }
        }
        w[i][12].z = 0.0f; w[i][12].w = 0.0f;  // pad cols 50,51
    }

    // bias / wx per row (meaning depends on half)
    float bw[4];
    #pragma unroll
    for (int i = 0; i < 4; ++i) {
        int r = rowbase + i;
        if (half == 0) {
            bw[i] = (r < 400) ? (bih0[r] + bhh0[r])
                  : (r < 800) ? (bih1[r-400] + bhh1[r-400]) : 0.0f;
        } else {
            bw[i] = (r < 400) ? Wih0[r] : 0.0f;
        }
    }
    const bool useX = (half == 1) && (rowbase < 400);

    // LDS-task preload (threads 0..351: row qid<176, this thread's half)
    float lb = 0.0f;
    if (tid < 2*NLDSROW) {
        lb = half ? Wih0[qid] : (bih0[qid] + bhh0[qid]);
    }

    // h source pointer for the register dot (uniform per thread; no straddle)
    const float4* hb4 = reinterpret_cast<const float4*>(
        ((rowbase < 800) ? h1_s : h2_s) + half*52);
    const float*  hp  = h1_s + half*52;     // LDS-task h (always h1), unpadded view

    const float wl = (tid < HH) ? Wlin[tid] : 0.0f;
    const int slotbase = qid + half*1024;
    float c0 = 0.0f, c1 = 0.0f;

    __syncthreads();

    for (int t = 0; t <= LL; ++t) {
        const float xt = x_s[(t < LL) ? t : (LL-1)];

        // === dot phase ===
        {
            float a0 = 0.f, a1 = 0.f, a2 = 0.f, a3 = 0.f;
            #pragma unroll
            for (int j = 0; j < 13; ++j) {
                float4 hv = hb4[j];
                a0 = fmaf(w[0][j].x, hv.x, a0); a0 = fmaf(w[0][j].y, hv.y, a0);
                a0 = fmaf(w[0][j].z, hv.z, a0); a0 = fmaf(w[0][j].w, hv.w, a0);
                a1 = fmaf(w[1][j].x, hv.x, a1); a1 = fmaf(w[1][j].y, hv.y, a1);
                a1 = fmaf(w[1][j].z, hv.z, a1); a1 = fmaf(w[1][j].w, hv.w, a1);
                a2 = fmaf(w[2][j].x, hv.x, a2); a2 = fmaf(w[2][j].y, hv.y, a2);
                a2 = fmaf(w[2][j].z, hv.z, a2); a2 = fmaf(w[2][j].w, hv.w, a2);
                a3 = fmaf(w[3][j].x, hv.x, a3); a3 = fmaf(w[3][j].y, hv.y, a3);
                a3 = fmaf(w[3][j].z, hv.z, a3); a3 = fmaf(w[3][j].w, hv.w, a3);
            }
            part_s[slotbase + 0*256] = a0 + (useX ? bw[0]*xt : bw[0]);
            part_s[slotbase + 1*256] = a1 + (useX ? bw[1]*xt : bw[1]);
            part_s[slotbase + 2*256] = a2 + (useX ? bw[2]*xt : bw[2]);
            part_s[slotbase + 3*256] = a3 + (useX ? bw[3]*xt : bw[3]);
        }
        // LDS-streamed rows 0..175 (these are L0 gates 0..175, h1 source)
        if (tid < 2*NLDSROW) {
            const float* wp = wq_s + (half*50)*NLDSROW + qid;
            float b0 = 0.f, b1 = 0.f;
            #pragma unroll
            for (int j = 0; j < 50; j += 2) {
                b0 = fmaf(wp[(j  )*NLDSROW], hp[j  ], b0);
                b1 = fmaf(wp[(j+1)*NLDSROW], hp[j+1], b1);
            }
            q_s[qid + half*NLDSROW] = b0 + b1 + (half ? lb*xt : lb);
        }
        __syncthreads();

        // === gating phase ===
        if (tid < HH) {                         // L0 gating -> h1(t)
            const int j = tid;
            float g[4];
            #pragma unroll
            for (int k = 0; k < 4; ++k) {
                int r = j + k*100;
                if (r < NLDSROW) {
                    g[k] = q_s[r] + q_s[r + NLDSROW];
                } else {
                    int rr = r - RB0;
                    int b  = (rr >> 2) + ((rr & 3) << 8);
                    g[k] = part_s[b] + part_s[b + 1024];
                }
            }
            c0 = sigmoidf_(g[1])*c0 + sigmoidf_(g[0])*tanhf_(g[2]);
            float h = sigmoidf_(g[3])*tanhf_(c0);
            h1_s[j + 2*(j >= 50)] = h;
        } else if (tid >= 128 && tid < 128 + HH) {   // L1 gating -> h2(t-1)
            if (t >= 1) {
                const int j = tid - 128;
                float v[4];
                #pragma unroll
                for (int k = 0; k < 4; ++k) {
                    int g = j + k*100;
                    int rr1 = (400 + g) - RB0;
                    int b1i = (rr1 >> 2) + ((rr1 & 3) << 8);
                    int rr2 = (800 + g) - RB0;
                    int b2i = (rr2 >> 2) + ((rr2 & 3) << 8);
                    v[k] = (part_s[b1i] + part_s[b1i + 1024])
                         + (part_s[b2i] + part_s[b2i + 1024]);
                }
                c1 = sigmoidf_(v[1])*c1 + sigmoidf_(v[0])*tanhf_(v[2]);
                h2_s[j + 2*(j >= 50)] = sigmoidf_(v[3])*tanhf_(c1);
            }
        }
        __syncthreads();
    }

    // ---- final projection: out = h2(L-1) . Wlin + blin ----
    if (tid < HH) part_s[tid] = wl * h2_s[tid + 2*(tid >= 50)];
    __syncthreads();
    if (tid == 0) {
        float s = 0.0f;
        for (int k = 0; k < HH; ++k) s += part_s[k];
        out[0] = s + blin[0];
    }
}

extern "C" void kernel_launch(void* const* d_in, const int* in_sizes, int n_in,
                              void* d_out, int out_size, void* d_ws, size_t ws_size,
                              hipStream_t stream) {
    (void)in_sizes; (void)n_in; (void)out_size; (void)d_ws; (void)ws_size;

    const float* x_seq = (const float*)d_in[0];
    const float* Wih0  = (const float*)d_in[1];
    const float* Whh0  = (const float*)d_in[2];
    const float* bih0  = (const float*)d_in[3];
    const float* bhh0  = (const float*)d_in[4];
    const float* Wih1  = (const float*)d_in[5];
    const float* Whh1  = (const float*)d_in[6];
    const float* bih1  = (const float*)d_in[7];
    const float* bhh1  = (const float*)d_in[8];
    const float* Wlin  = (const float*)d_in[9];
    const float* blin  = (const float*)d_in[10];
    float* out = (float*)d_out;

    static bool attr_set = false;
    if (!attr_set) {
        hipFuncSetAttribute((const void*)lstm_half_kernel,
                            hipFuncAttributeMaxDynamicSharedMemorySize,
                            LDS_FLOATS * (int)sizeof(float));
        attr_set = true;
    }

    hipLaunchKernelGGL(lstm_half_kernel, dim3(1), dim3(NT),
                       LDS_FLOATS * sizeof(float), stream,
                       x_seq, Wih0, Whh0, bih0, bhh0,
                       Wih1, Whh1, bih1, bhh1, Wlin, blin, out);
}

// Round 4
// 7129.922 us; speedup vs baseline: 8.0087x; 1.2223x over previous
//
#include <hip/hip_runtime.h>

#define HH   100
#define LL   4096
#define NT   512
#define NLDSROW 176          // W_all rows 0..175 (= Whh0 gates 0..175) streamed from LDS
#define RB0  176             // first register-resident row
// W_all rows: [0,400) Whh0 (h1), [400,800) Wih1 (h1), [800,1200) Whh1 (h2)
// Each thread: 4 rows x one k-half (50 cols padded to 52) in 52 NAMED float4s (no alloca!).

// LDS floats: x[4096] wq2[50*176*2] h1[104] h2[104] part[2048] q[352]
#define LDS_FLOATS (4096 + 17600 + 104 + 104 + 2048 + 352)

__device__ __forceinline__ float sigmoidf_(float x) {
    return 1.0f / (1.0f + __expf(-x));
}
__device__ __forceinline__ float tanhf_(float x) {
    return 1.0f - 2.0f / (__expf(2.0f * x) + 1.0f);
}

// ---- named register-weight machinery (kills AMDGPUPromoteAlloca scratch) ----
#define DECL_ROW(n) float4 n##0,n##1,n##2,n##3,n##4,n##5,n##6,n##7,n##8,n##9,n##10,n##11,n##12;
#define LOAD_PAIR(dst, s2, k) { float2 u0=(s2)[2*(k)], u1=(s2)[2*(k)+1]; dst = make_float4(u0.x,u0.y,u1.x,u1.y); }
#define LOAD_ROW(n, P) { const float2* s2_ = reinterpret_cast<const float2*>(P); \
  LOAD_PAIR(n##0,s2_,0) LOAD_PAIR(n##1,s2_,1) LOAD_PAIR(n##2,s2_,2) LOAD_PAIR(n##3,s2_,3) \
  LOAD_PAIR(n##4,s2_,4) LOAD_PAIR(n##5,s2_,5) LOAD_PAIR(n##6,s2_,6) LOAD_PAIR(n##7,s2_,7) \
  LOAD_PAIR(n##8,s2_,8) LOAD_PAIR(n##9,s2_,9) LOAD_PAIR(n##10,s2_,10) LOAD_PAIR(n##11,s2_,11) \
  { float2 u0=s2_[24]; n##12 = make_float4(u0.x,u0.y,0.0f,0.0f); } }
#define FMA4(wv, hv, acc) acc=fmaf((wv).x,(hv).x,acc); acc=fmaf((wv).y,(hv).y,acc); \
                          acc=fmaf((wv).z,(hv).z,acc); acc=fmaf((wv).w,(hv).w,acc);
#define STEP(j) { float4 hv = hb4[j]; FMA4(wa_##j,hv,a0) FMA4(wb_##j,hv,a1) \
                                      FMA4(wc_##j,hv,a2) FMA4(wd_##j,hv,a3) }

__global__ __attribute__((amdgpu_flat_work_group_size(NT, NT)))
           __attribute__((amdgpu_waves_per_eu(2, 2)))
void lstm_named_kernel(const float* __restrict__ x_seq,
                       const float* __restrict__ Wih0,
                       const float* __restrict__ Whh0,
                       const float* __restrict__ bih0,
                       const float* __restrict__ bhh0,
                       const float* __restrict__ Wih1,
                       const float* __restrict__ Whh1,
                       const float* __restrict__ bih1,
                       const float* __restrict__ bhh1,
                       const float* __restrict__ Wlin,
                       const float* __restrict__ blin,
                       float* __restrict__ out)
{
    extern __shared__ float lds[];
    float*  x_s    = lds;                      // [4096]
    float2* wq2    = reinterpret_cast<float2*>(lds + LL);   // [50][176] float2: {W[r][2p],W[r][2p+1]} at wq2[p*176+r]
    float*  h1_s   = lds + LL + 17600;         // [104] padded: h[e] at e + 2*(e>=50)
    float*  h2_s   = h1_s + 104;               // [104]
    float*  part_s = h2_s + 104;               // [2048]: slot = ((row-176)>>2) + ((row-176)&3)*256 + half*1024
    float*  q_s    = part_s + 2048;            // [352]: row + 176*half

    const int tid  = threadIdx.x;
    const int half = tid & 1;
    const int qid  = tid >> 1;                 // 0..255
    const int rowbase = RB0 + 4*qid;           // 176..1196, region-aligned

    // ---- prologue: x (coalesced) ----
    {
        const float4* src = reinterpret_cast<const float4*>(x_seq);
        float4*       dst = reinterpret_cast<float4*>(x_s);
        for (int i = tid; i < LL/4; i += NT) dst[i] = src[i];
    }
    // ---- wq2: pair-transposed Whh0 rows 0..175 (coalesced global read) ----
    for (int idx = tid; idx < NLDSROW*50; idx += NT) {
        int r = idx / 50, p = idx % 50;
        float2 v = *reinterpret_cast<const float2*>(Whh0 + r*HH + 2*p);
        wq2[p*NLDSROW + r] = v;
    }
    if (tid < 104) { h1_s[tid] = 0.0f; h2_s[tid] = 0.0f; }

    // ---- per-thread register weights: 4 rows x 52 (padded), NAMED float4s ----
    const float* M; int r0;
    if (rowbase < 400)      { M = Whh0; r0 = rowbase; }
    else if (rowbase < 800) { M = Wih1; r0 = rowbase - 400; }
    else                    { M = Whh1; r0 = rowbase - 800; }

    DECL_ROW(wa_) DECL_ROW(wb_) DECL_ROW(wc_) DECL_ROW(wd_)
    LOAD_ROW(wa_, M + (r0+0)*HH + half*50)
    LOAD_ROW(wb_, M + (r0+1)*HH + half*50)
    LOAD_ROW(wc_, M + (r0+2)*HH + half*50)
    LOAD_ROW(wd_, M + (r0+3)*HH + half*50)

    // bias / wx per row (meaning depends on half; multiplied by xvs = half? xt : 1)
    float bw[4];
    #pragma unroll
    for (int i = 0; i < 4; ++i) {
        int r = rowbase + i;
        if (half == 0) {
            bw[i] = (r < 400) ? (bih0[r] + bhh0[r])
                  : (r < 800) ? (bih1[r-400] + bhh1[r-400]) : 0.0f;
        } else {
            bw[i] = (r < 400) ? Wih0[r] : 0.0f;
        }
    }

    // LDS-task constants (threads 0..351: row qid<176, this thread's half)
    float lb = 0.0f;
    if (tid < 2*NLDSROW) {
        lb = half ? Wih0[qid] : (bih0[qid] + bhh0[qid]);
    }

    const float4* hb4 = reinterpret_cast<const float4*>(
        ((rowbase < 800) ? h1_s : h2_s) + half*52);
    const float2* hp2 = reinterpret_cast<const float2*>(h1_s + half*52);

    const float wl = (tid < HH) ? Wlin[tid] : 0.0f;
    const int slotbase = qid + half*1024;
    float c0 = 0.0f, c1 = 0.0f;

    __syncthreads();

    for (int t = 0; t <= LL; ++t) {
        const float xt  = x_s[(t < LL) ? t : (LL-1)];
        const float xvs = half ? xt : 1.0f;

        // === dot phase: 4 register rows (one k-half each) ===
        {
            float a0 = 0.f, a1 = 0.f, a2 = 0.f, a3 = 0.f;
            STEP(0) STEP(1) STEP(2) STEP(3) STEP(4) STEP(5) STEP(6)
            STEP(7) STEP(8) STEP(9) STEP(10) STEP(11) STEP(12)
            part_s[slotbase + 0*256] = fmaf(bw[0], xvs, a0);
            part_s[slotbase + 1*256] = fmaf(bw[1], xvs, a1);
            part_s[slotbase + 2*256] = fmaf(bw[2], xvs, a2);
            part_s[slotbase + 3*256] = fmaf(bw[3], xvs, a3);
        }
        // === LDS-streamed rows 0..175 (L0 gates 0..175, h1 source), float2 pairs ===
        if (tid < 2*NLDSROW) {
            const float2* wp = wq2 + 25*half*NLDSROW + qid;
            float b0 = 0.f, b1 = 0.f;
            #pragma unroll
            for (int p = 0; p < 25; ++p) {
                float2 wv = wp[p*NLDSROW];
                float2 hv = hp2[p];
                b0 = fmaf(wv.x, hv.x, b0);
                b1 = fmaf(wv.y, hv.y, b1);
            }
            q_s[qid + half*NLDSROW] = fmaf(lb, xvs, b0 + b1);
        }
        __syncthreads();

        // === gating phase ===
        if (tid < HH) {                          // L0 gating -> h1(t)
            const int j = tid;
            float g[4];
            #pragma unroll
            for (int k = 0; k < 4; ++k) {
                int r = j + k*100;
                if (r < NLDSROW) {
                    g[k] = q_s[r] + q_s[r + NLDSROW];
                } else {
                    int rr = r - RB0;
                    int b  = (rr >> 2) + ((rr & 3) << 8);
                    g[k] = part_s[b] + part_s[b + 1024];
                }
            }
            if (t < LL) {
                c0 = sigmoidf_(g[1])*c0 + sigmoidf_(g[0])*tanhf_(g[2]);
                h1_s[j + 2*(j >= 50)] = sigmoidf_(g[3])*tanhf_(c0);
            }
        } else if (tid >= 128 && tid < 128 + HH) {   // L1 gating -> h2(t-1)
            if (t >= 1) {
                const int j = tid - 128;
                float v[4];
                #pragma unroll
                for (int k = 0; k < 4; ++k) {
                    int g = j + k*100;
                    int rr1 = (400 + g) - RB0;
                    int b1i = (rr1 >> 2) + ((rr1 & 3) << 8);
                    int rr2 = (800 + g) - RB0;
                    int b2i = (rr2 >> 2) + ((rr2 & 3) << 8);
                    v[k] = (part_s[b1i] + part_s[b1i + 1024])
                         + (part_s[b2i] + part_s[b2i + 1024]);
                }
                c1 = sigmoidf_(v[1])*c1 + sigmoidf_(v[0])*tanhf_(v[2]);
                h2_s[j + 2*(j >= 50)] = sigmoidf_(v[3])*tanhf_(c1);
            }
        }
        __syncthreads();
    }

    // ---- final projection: out = h2(L-1) . Wlin + blin ----
    if (tid < HH) part_s[tid] = wl * h2_s[tid + 2*(tid >= 50)];
    __syncthreads();
    if (tid == 0) {
        float s = 0.0f;
        for (int k = 0; k < HH; ++k) s += part_s[k];
        out[0] = s + blin[0];
    }
}

extern "C" void kernel_launch(void* const* d_in, const int* in_sizes, int n_in,
                              void* d_out, int out_size, void* d_ws, size_t ws_size,
                              hipStream_t stream) {
    (void)in_sizes; (void)n_in; (void)out_size; (void)d_ws; (void)ws_size;

    const float* x_seq = (const float*)d_in[0];
    const float* Wih0  = (const float*)d_in[1];
    const float* Whh0  = (const float*)d_in[2];
    const float* bih0  = (const float*)d_in[3];
    const float* bhh0  = (const float*)d_in[4];
    const float* Wih1  = (const float*)d_in[5];
    const float* Whh1  = (const float*)d_in[6];
    const float* bih1  = (const float*)d_in[7];
    const float* bhh1  = (const float*)d_in[8];
    const float* Wlin  = (const float*)d_in[9];
    const float* blin  = (const float*)d_in[10];
    float* out = (float*)d_out;

    static bool attr_set = false;
    if (!attr_set) {
        hipFuncSetAttribute((const void*)lstm_named_kernel,
                            hipFuncAttributeMaxDynamicSharedMemorySize,
                            LDS_FLOATS * (int)sizeof(float));
        attr_set = true;
    }

    hipLaunchKernelGGL(lstm_named_kernel, dim3(1), dim3(NT),
                       LDS_FLOATS * sizeof(float), stream,
                       x_seq, Wih0, Whh0, bih0, bhh0,
                       Wih1, Whh1, bih1, bhh1, Wlin, blin, out);
}